// Round 16
// baseline (342.677 us; speedup 1.0000x reference)
//
#include <hip/hip_runtime.h>
#include <math.h>

// ---------------- problem constants ----------------
#define BB 16
#define NBOX 588          // A * 14 * 14
#define TOPJ 392          // J
#define TOPK 196          // K
#define EMBED 768

typedef unsigned short u16;
typedef unsigned int   u32;
using short8 = __attribute__((ext_vector_type(8))) short;
using f32x4  = __attribute__((ext_vector_type(4))) float;

// ---------------- bf16 split helpers ----------------
__device__ inline u16 rnebf(float x) {
    u32 u = __builtin_bit_cast(u32, x);
    u32 r = u + 0x7fff + ((u >> 16) & 1);
    return (u16)(r >> 16);
}
__device__ inline float bfval(u16 h) {
    u32 u = ((u32)h) << 16;
    return __builtin_bit_cast(float, u);
}
// packed-limb unpack: word = (limb0 << 16) | limb1
__device__ inline u32 hi2(u32 w0, u32 w1) { return (w0 >> 16) | (w1 & 0xffff0000u); }
__device__ inline u32 lo2(u32 w0, u32 w1) { return (w0 & 0xffffu) | (w1 << 16); }

// ================= fused weight transform + split (1 launch) =================
__global__ void w_split_all(
    const float* __restrict__ rw1, const float* __restrict__ rw2,
    const float* __restrict__ rw3, const float* __restrict__ rw4,
    const float* __restrict__ pw1, const float* __restrict__ pw2,
    const float* __restrict__ pw3,
    float* t1, float* t4, float* q1,
    u16* w2h, u16* w2m, u16* w2l,
    u16* w3h, u16* w3m, u16* w3l,
    u16* p2h, u16* p2l, u16* p3h, u16* p3l)
{
    int i = blockIdx.x * 256 + threadIdx.x;
    if (i < 1728) {        // rw1: Cout=64, Cin=3, KK=9 (conv-order fp32)
        int oc = i % 64; int k = i / 64; int tap = k % 9; int ic = k / 9;
        t1[i] = rw1[(oc * 3 + ic) * 9 + tap];
        return;
    }
    i -= 1728;
    if (i < 73728) {       // rw2: 128 x (9*64), split3
        int oc = i / 576; int rem = i - oc * 576; int tap = rem >> 6; int ic = rem & 63;
        float v = rw2[(oc * 64 + ic) * 9 + tap];
        u16 h = rnebf(v); float r = v - bfval(h);
        u16 m = rnebf(r); float r2 = r - bfval(m);
        w2h[i] = h; w2m[i] = m; w2l[i] = rnebf(r2);
        return;
    }
    i -= 73728;
    if (i < 294912) {      // rw3: 256 x (9*128), split3
        int oc = i / 1152; int rem = i - oc * 1152; int tap = rem >> 7; int ic = rem & 127;
        float v = rw3[(oc * 128 + ic) * 9 + tap];
        u16 h = rnebf(v); float r = v - bfval(h);
        u16 m = rnebf(r); float r2 = r - bfval(m);
        w3h[i] = h; w3m[i] = m; w3l[i] = rnebf(r2);
        return;
    }
    i -= 294912;
    if (i < 6912) {        // rw4: [oc*9+tap][256] fp32
        int ic = i % 256; int t = i / 256; int tap = t % 9; int oc = t / 9;
        t4[i] = rw4[(oc * 256 + ic) * 9 + tap];
        return;
    }
    i -= 6912;
    if (i < 3072) {        // pw1: Cout=64, Cin=3, KK=16 (conv-order fp32)
        int oc = i % 64; int k = i / 64; int tap = k % 16; int ic = k / 16;
        q1[i] = pw1[(oc * 3 + ic) * 16 + tap];
        return;
    }
    i -= 3072;
    if (i < 32768) {       // pw2: 128 x (4*64), split2
        int oc = i >> 8; int rem = i & 255; int tap = rem >> 6; int ic = rem & 63;
        float v = pw2[(oc * 64 + ic) * 4 + tap];
        u16 h = rnebf(v);
        p2h[i] = h; p2l[i] = rnebf(v - bfval(h));
        return;
    }
    i -= 32768;
    if (i < 393216) {      // pw3: 768 x (4*128), split2
        int oc = i >> 9; int rem = i & 511; int tap = rem >> 7; int ic = rem & 127;
        float v = pw3[(oc * 128 + ic) * 4 + tap];
        u16 h = rnebf(v);
        p3h[i] = h; p3l[i] = rnebf(v - bfval(h));
        return;
    }
}

// ================= activation splitters =================
__global__ void split3_bn(float* __restrict__ x, u16* __restrict__ lp,
                          const float* __restrict__ coef, int Cmask, long n4) {
    long i = (long)blockIdx.x * 256 + threadIdx.x;
    if (i >= n4) return;
    float4 v = *reinterpret_cast<const float4*>(x + i * 4);
    int c0 = (int)((i * 4) & Cmask);
    float4 sc = *reinterpret_cast<const float4*>(coef + c0);
    float4 sh = *reinterpret_cast<const float4*>(coef + (Cmask + 1) + c0);
    float y[4] = {fmaxf(fmaf(v.x, sc.x, sh.x), 0.f), fmaxf(fmaf(v.y, sc.y, sh.y), 0.f),
                  fmaxf(fmaf(v.z, sc.z, sh.z), 0.f), fmaxf(fmaf(v.w, sc.w, sh.w), 0.f)};
    u32 w[4]; u16 l[4];
#pragma unroll
    for (int j = 0; j < 4; ++j) {
        u16 h = rnebf(y[j]); float r = y[j] - bfval(h);
        u16 m = rnebf(r);    float r2 = r - bfval(m);
        l[j] = rnebf(r2);
        w[j] = ((u32)h << 16) | (u32)m;
    }
    uint4 wv; wv.x = w[0]; wv.y = w[1]; wv.z = w[2]; wv.w = w[3];
    *reinterpret_cast<uint4*>(x + i * 4) = wv;
    uint2 lv; lv.x = (u32)l[0] | ((u32)l[1] << 16); lv.y = (u32)l[2] | ((u32)l[3] << 16);
    *reinterpret_cast<uint2*>(lp + i * 4) = lv;
}

__global__ void split2_plain(float* __restrict__ x, long n4) {
    long i = (long)blockIdx.x * 256 + threadIdx.x;
    if (i >= n4) return;
    float4 v = *reinterpret_cast<const float4*>(x + i * 4);
    float y[4] = {v.x, v.y, v.z, v.w};
    u32 w[4];
#pragma unroll
    for (int j = 0; j < 4; ++j) {
        u16 h = rnebf(y[j]);
        u16 l = rnebf(y[j] - bfval(h));
        w[j] = ((u32)h << 16) | (u32)l;
    }
    uint4 wv; wv.x = w[0]; wv.y = w[1]; wv.z = w[2]; wv.w = w[3];
    *reinterpret_cast<uint4*>(x + i * 4) = wv;
}

// ================= direct conv, NCHW in (3ch), NHWC out =================
// STATS: per-block per-channel sum/sumsq of y via wave shfl reduce ->
// psum[c][blockIdx.x] (784 fixed-order partials; bn_coef_par reduces).
template<int KH, int KW, int S, int P, int OCT, bool STATS>
__global__ __launch_bounds__(256) void conv_direct_nhwc(
    const float* __restrict__ in, const float* __restrict__ wT,
    const float* __restrict__ bias, float* __restrict__ out,
    float* __restrict__ psum, float* __restrict__ psq, int NPART,
    int Cin, int Hin, int Win, int Cout, int Hout, int Wout)
{
    const int hw = Hout * Wout;
    const long total = (long)BB * hw;
    long sp = (long)blockIdx.x * 256 + threadIdx.x;
    if (sp >= total) return;           // never taken for our launches (total % 256 == 0 per grid)
    int b  = (int)(sp / hw);
    int r  = (int)(sp - (long)b * hw);
    int oy = r / Wout;
    int ox = r - oy * Wout;
    int oc0 = blockIdx.y * OCT;

    float acc[OCT];
#pragma unroll
    for (int i = 0; i < OCT; ++i) acc[i] = bias[oc0 + i];

    int  ixc[KW]; long yoff[KH]; float xm[KW], ym[KH];
#pragma unroll
    for (int kx = 0; kx < KW; ++kx) {
        int ix = ox * S - P + kx;
        xm[kx] = (ix >= 0 && ix < Win) ? 1.f : 0.f;
        ixc[kx] = min(max(ix, 0), Win - 1);
    }
#pragma unroll
    for (int ky = 0; ky < KH; ++ky) {
        int iy = oy * S - P + ky;
        ym[ky] = (iy >= 0 && iy < Hin) ? 1.f : 0.f;
        yoff[ky] = (long)min(max(iy, 0), Hin - 1) * Win;
    }

    const float* ib = in + (long)b * Cin * Hin * Win;
    for (int ic = 0; ic < Cin; ++ic) {
        const float* ip = ib + (long)ic * Hin * Win;
#pragma unroll
        for (int ky = 0; ky < KH; ++ky) {
            const float* row = ip + yoff[ky];
#pragma unroll
            for (int kx = 0; kx < KW; ++kx) {
                float v = row[ixc[kx]];
                if (P > 0) v *= ym[ky] * xm[kx];
                const float* wr = wT + ((long)((ic * KH + ky) * KW + kx)) * Cout + oc0;
#pragma unroll
                for (int i = 0; i < OCT; ++i) acc[i] = fmaf(v, wr[i], acc[i]);
            }
        }
    }
    float* op = out + sp * Cout + oc0;
#pragma unroll
    for (int i = 0; i < OCT; i += 4) {
        float4 v = {acc[i], acc[i+1], acc[i+2], acc[i+3]};
        *reinterpret_cast<float4*>(op + i) = v;
    }

    if (STATS) {
        // wave reduce each channel's y and y^2 across 64 lanes, then cross-wave via LDS
        __shared__ float sred[4][OCT], qred[4][OCT];
        const int tid = threadIdx.x;
        const int wv = tid >> 6;
        const int ln = tid & 63;
#pragma unroll
        for (int i = 0; i < OCT; ++i) {
            float s = acc[i];
            float q = acc[i] * acc[i];
            for (int o = 32; o > 0; o >>= 1) {
                s += __shfl_down(s, o);
                q += __shfl_down(q, o);
            }
            if (ln == 0) { sred[wv][i] = s; qred[wv][i] = q; }
        }
        __syncthreads();
        if (tid < OCT) {
            float s = sred[0][tid] + sred[1][tid] + sred[2][tid] + sred[3][tid];
            float q = qred[0][tid] + qred[1][tid] + qred[2][tid] + qred[3][tid];
            int c = oc0 + tid;
            psum[(long)c * NPART + blockIdx.x] = s;
            psq [(long)c * NPART + blockIdx.x] = q;
        }
    }
}

// ================= split-bf16 MFMA implicit-GEMM conv (pre-split A) =================
// BM=64 x BN=64 (small tile for occupancy: 24KB LDS -> 6 blocks/CU = 24 waves/CU).
// Bijective XCD-chunk swizzle + n-inner decode (L2 A-panel share).
// 4 waves as 2x2, wave tile 32x32. Per-thread staging: 1 slot (8 k-elems) of A+B.
// STATS: per-block per-channel sum/sumsq -> psum[c][mt] (fixed-order reduce).
#define MBM 64
#define MBN 64
template<int KH, int KW, int S, int P, int CLOG, int NS, bool STATS>
__global__ __launch_bounds__(256, 6) void mfma_conv7(
    const u32* __restrict__ hm, const u16* __restrict__ lp,
    const u16* __restrict__ w0, const u16* __restrict__ w1, const u16* __restrict__ w2,
    const float* __restrict__ bias, float* __restrict__ out,
    float* __restrict__ psum, float* __restrict__ psq, int NT,
    int Hin, int Win, int Cout, int Hout, int Wout)
{
    const int Cin = 1 << CLOG;
    const int KK = KH * KW;
    const int Ktot = Cin * KK;
    const int hw = Hout * Wout;
    const long Mtot = (long)BB * hw;

    // ---- bijective XCD-chunk swizzle + n-inner decode ----
    const int nwg = gridDim.x;
    const int orig = blockIdx.x;
    const int xcd = orig & 7, pos = orig >> 3;
    const int qc = nwg >> 3, rc = nwg & 7;
    const int logical = (xcd < rc ? xcd * (qc + 1) : rc * (qc + 1) + (xcd - rc) * qc) + pos;
    const int MT = nwg / NT;
    const int mt = logical / NT;
    const int nt = logical - mt * NT;
    const int n0 = nt * MBN;
    const long m0 = (long)mt * MBM;

    __shared__ u16 Asm[NS][MBM * 32];
    __shared__ u16 Bsm[NS][MBN * 32];

    const int tid = threadIdx.x;

    // ---- staging ids: row = tid>>2 (0..63), slot = tid&3 (8 k-elems = 16B) ----
    const int srow = tid >> 2;
    const int slot = tid & 3;
    long sp_g = m0 + srow; if (sp_g >= Mtot) sp_g = Mtot - 1;
    const int gb  = (int)(sp_g / hw);
    const int gr  = (int)(sp_g - (long)gb * hw);
    const int goy = gr / Wout;
    const int gox = gr - goy * Wout;
    const long ibase_e = (long)gb * Hin * Win * Cin;

    uint4 ga0, ga1, gal, b0r, b1r, b2r;

    auto gatherA = [&](int k0) {
        int tap = k0 >> CLOG;
        int ky = tap / KW, kx = tap - ky * KW;
        int icb = (k0 & (Cin - 1)) + slot * 8;
        int iy = goy * S - P + ky;
        int ix = gox * S - P + kx;
        bool ok = true;
        if (P > 0) {
            ok = (iy >= 0 && iy < Hin && ix >= 0 && ix < Win);
            iy = min(max(iy, 0), Hin - 1);
            ix = min(max(ix, 0), Win - 1);
        }
        long e = ibase_e + ((long)iy * Win + ix) * Cin + icb;
        const uint4* ph = reinterpret_cast<const uint4*>(hm + e);   // 8 u32 = 32B
        ga0 = ph[0]; ga1 = ph[1];
        if constexpr (NS == 3)
            gal = *reinterpret_cast<const uint4*>(lp + e);          // 8 u16 = 16B
        if (P > 0 && !ok) {
            uint4 z; z.x = z.y = z.z = z.w = 0u;
            ga0 = z; ga1 = z;
            if constexpr (NS == 3) gal = z;
        }
    };
    auto gatherB = [&](int k0) {
        long eb = (long)(n0 + srow) * Ktot + k0 + slot * 8;
        b0r = *reinterpret_cast<const uint4*>(w0 + eb);
        b1r = *reinterpret_cast<const uint4*>(w1 + eb);
        if constexpr (NS == 3) b2r = *reinterpret_cast<const uint4*>(w2 + eb);
    };
    auto stage = [&]() {
        const int sw = (srow >> 1) & 3;
        const int o = srow * 32 + ((slot ^ sw) << 3);
        uint4 H, M;
        H.x = hi2(ga0.x, ga0.y); H.y = hi2(ga0.z, ga0.w);
        H.z = hi2(ga1.x, ga1.y); H.w = hi2(ga1.z, ga1.w);
        M.x = lo2(ga0.x, ga0.y); M.y = lo2(ga0.z, ga0.w);
        M.z = lo2(ga1.x, ga1.y); M.w = lo2(ga1.z, ga1.w);
        *reinterpret_cast<uint4*>(&Asm[0][o]) = H;
        *reinterpret_cast<uint4*>(&Asm[1][o]) = M;
        if constexpr (NS == 3) *reinterpret_cast<uint4*>(&Asm[2][o]) = gal;
        *reinterpret_cast<uint4*>(&Bsm[0][o]) = b0r;
        *reinterpret_cast<uint4*>(&Bsm[1][o]) = b1r;
        if constexpr (NS == 3) *reinterpret_cast<uint4*>(&Bsm[2][o]) = b2r;
    };

    // ---- compute ids: 4 waves 2x2, wave tile 32x32 ----
    const int w    = tid >> 6;
    const int lane = tid & 63;
    const int wr = w >> 1, wc = w & 1;
    const int l15 = lane & 15;
    const int sl  = lane >> 4;

    f32x4 acc[2][2];
#pragma unroll
    for (int f = 0; f < 2; ++f)
#pragma unroll
        for (int g = 0; g < 2; ++g) acc[f][g] = (f32x4){0.f, 0.f, 0.f, 0.f};

    auto computeChunk = [&]() {
        short8 bfr[2][NS];
#pragma unroll
        for (int g = 0; g < 2; ++g) {
            int br = wc * 32 + g * 16 + l15;
            int bo = br * 32 + ((sl ^ ((br >> 1) & 3)) << 3);
#pragma unroll
            for (int s = 0; s < NS; ++s)
                bfr[g][s] = __builtin_bit_cast(short8,
                    *reinterpret_cast<const uint4*>(&Bsm[s][bo]));
        }
#pragma unroll
        for (int f = 0; f < 2; ++f) {
            int ar = wr * 32 + f * 16 + l15;
            int ao = ar * 32 + ((sl ^ ((ar >> 1) & 3)) << 3);
            short8 a0 = __builtin_bit_cast(short8,
                *reinterpret_cast<const uint4*>(&Asm[0][ao]));
            short8 a1 = __builtin_bit_cast(short8,
                *reinterpret_cast<const uint4*>(&Asm[1][ao]));
            short8 a2;
            if constexpr (NS == 3)
                a2 = __builtin_bit_cast(short8,
                    *reinterpret_cast<const uint4*>(&Asm[2][ao]));
#pragma unroll
            for (int g = 0; g < 2; ++g) {
                acc[f][g] = __builtin_amdgcn_mfma_f32_16x16x32_bf16(a0, bfr[g][0], acc[f][g], 0, 0, 0);
                acc[f][g] = __builtin_amdgcn_mfma_f32_16x16x32_bf16(a0, bfr[g][1], acc[f][g], 0, 0, 0);
                acc[f][g] = __builtin_amdgcn_mfma_f32_16x16x32_bf16(a1, bfr[g][0], acc[f][g], 0, 0, 0);
                if constexpr (NS == 3) {
                    acc[f][g] = __builtin_amdgcn_mfma_f32_16x16x32_bf16(a1, bfr[g][1], acc[f][g], 0, 0, 0);
                    acc[f][g] = __builtin_amdgcn_mfma_f32_16x16x32_bf16(a0, bfr[g][2], acc[f][g], 0, 0, 0);
                    acc[f][g] = __builtin_amdgcn_mfma_f32_16x16x32_bf16(a2, bfr[g][0], acc[f][g], 0, 0, 0);
                }
            }
        }
    };

    const int nch = Ktot / 32;
    gatherA(0); gatherB(0);
    for (int c = 0; c < nch; ++c) {
        __syncthreads();                    // prev compute done reading LDS
        stage();
        __syncthreads();                    // tile staged
        if (c + 1 < nch) { gatherA((c + 1) * 32); gatherB((c + 1) * 32); }
        computeChunk();
    }

    // ---- epilogue: C frag layout col=lane&15, row=(lane>>4)*4+reg ----
    float bv[2];
#pragma unroll
    for (int g = 0; g < 2; ++g) bv[g] = bias[n0 + wc * 32 + g * 16 + l15];
    float ss[2] = {0.f, 0.f}, qq[2] = {0.f, 0.f};
#pragma unroll
    for (int f = 0; f < 2; ++f) {
        long row0 = m0 + wr * 32 + f * 16 + sl * 4;
#pragma unroll
        for (int g = 0; g < 2; ++g) {
            int col = n0 + wc * 32 + g * 16 + l15;
#pragma unroll
            for (int r = 0; r < 4; ++r) {
                long row = row0 + r;
                float y = acc[f][g][r] + bv[g];
                if (row < Mtot) out[row * (long)Cout + col] = y;
                if (STATS) { ss[g] += y; qq[g] += y * y; }
            }
        }
    }
    if (STATS) {
        __syncthreads();                        // Asm free now
        float* st = reinterpret_cast<float*>(&Asm[0][0]);   // [64][8]
        float* sq = st + MBN * 8;
        int slotc = wr * 4 + sl;
#pragma unroll
        for (int g = 0; g < 2; ++g) {
            int cl = wc * 32 + g * 16 + l15;
            st[cl * 8 + slotc] = ss[g];
            sq[cl * 8 + slotc] = qq[g];
        }
        __syncthreads();
        if (tid < MBN) {
            float sAcc = 0.f, qAcc = 0.f;
            for (int j = 0; j < 8; ++j) { sAcc += st[tid * 8 + j]; qAcc += sq[tid * 8 + j]; }
            int c = n0 + tid;
            psum[(long)c * MT + mt] = sAcc;
            psq [(long)c * MT + mt] = qAcc;
        }
    }
}

// parallel bn_coef: one block per channel; strided + tree reduce (fixed order).
__global__ void bn_coef_par(const float* __restrict__ psum, const float* __restrict__ psq,
                            const float* __restrict__ gamma, const float* __restrict__ beta,
                            float* __restrict__ coef, int C, float inv_cnt, int nparts) {
    int c = blockIdx.x;
    int tid = threadIdx.x;
    float s = 0.f, q = 0.f;
    for (int p = tid; p < nparts; p += 256) {
        s += psum[(long)c * nparts + p];
        q += psq [(long)c * nparts + p];
    }
    __shared__ float sd[256], qd[256];
    sd[tid] = s; qd[tid] = q;
    __syncthreads();
    for (int o = 128; o > 0; o >>= 1) {
        if (tid < o) { sd[tid] += sd[tid + o]; qd[tid] += qd[tid + o]; }
        __syncthreads();
    }
    if (tid == 0) {
        float mean = sd[0] * inv_cnt;
        float var  = qd[0] * inv_cnt - mean * mean;
        float sc = gamma[c] * rsqrtf(var + 1e-5f);
        coef[c] = sc;
        coef[C + c] = beta[c] - mean * sc;
    }
}

// ================= score conv (rp4): tap-parallel partials + reduce =================
__global__ void score_partial(const float* __restrict__ r3, const float* __restrict__ wT4,
                              const float* __restrict__ coef, float* __restrict__ part) {
    int idx = blockIdx.x * 256 + threadIdx.x;
    if (idx >= 9 * 3136) return;
    int tap = idx / 3136;
    int sp  = idx - tap * 3136;
    int b = sp / 196; int pos = sp - b * 196;
    int oy = pos / 14, ox = pos - oy * 14;
    int ky = tap / 3, kx = tap - ky * 3;
    int iy = oy * 2 - 1 + ky, ix = ox * 2 - 1 + kx;
    float mval = (iy >= 0 && iy < 28 && ix >= 0 && ix < 28) ? 1.f : 0.f;
    iy = min(max(iy, 0), 27); ix = min(max(ix, 0), 27);
    const float* p = r3 + ((long)(b * 28 + iy) * 28 + ix) * 256;
    float a0 = 0.f, a1 = 0.f, a2 = 0.f;
    for (int icv = 0; icv < 64; ++icv) {
        float4 v  = *reinterpret_cast<const float4*>(p + icv * 4);
        float4 sc = *reinterpret_cast<const float4*>(coef + icv * 4);
        float4 sh = *reinterpret_cast<const float4*>(coef + 256 + icv * 4);
        float u[4];
        u[0] = fmaxf(fmaf(v.x, sc.x, sh.x), 0.f);
        u[1] = fmaxf(fmaf(v.y, sc.y, sh.y), 0.f);
        u[2] = fmaxf(fmaf(v.z, sc.z, sh.z), 0.f);
        u[3] = fmaxf(fmaf(v.w, sc.w, sh.w), 0.f);
        float4 w0 = *reinterpret_cast<const float4*>(wT4 + ((0 * 9 + tap) * 256 + icv * 4));
        float4 w1 = *reinterpret_cast<const float4*>(wT4 + ((1 * 9 + tap) * 256 + icv * 4));
        float4 w2 = *reinterpret_cast<const float4*>(wT4 + ((2 * 9 + tap) * 256 + icv * 4));
        a0 += u[0]*w0.x + u[1]*w0.y + u[2]*w0.z + u[3]*w0.w;
        a1 += u[0]*w1.x + u[1]*w1.y + u[2]*w1.z + u[3]*w1.w;
        a2 += u[0]*w2.x + u[1]*w2.y + u[2]*w2.z + u[3]*w2.w;
    }
    part[idx * 3 + 0] = a0 * mval;
    part[idx * 3 + 1] = a1 * mval;
    part[idx * 3 + 2] = a2 * mval;
}

__global__ void score_reduce(const float* __restrict__ part, const float* __restrict__ rb4,
                             float* __restrict__ score) {
    int idx = blockIdx.x * 256 + threadIdx.x;   // 3136*3
    if (idx >= 9408) return;
    int sp = idx / 3; int oc = idx - sp * 3;
    float s = rb4[oc];
    for (int t = 0; t < 9; ++t) s += part[((long)t * 3136 + sp) * 3 + oc];
    int b = sp / 196, pos = sp - b * 196;
    score[b * NBOX + oc * 196 + pos] = s;
}

// ================= top-K (stable ascending rank) + gate =================
__global__ void topk_kernel(const float* __restrict__ score, int* __restrict__ sel,
                            float* __restrict__ gate) {
    int b = blockIdx.x;
    int tid = threadIdx.x;
    __shared__ float s[NBOX];
    __shared__ float red[4];
    for (int n = tid; n < NBOX; n += blockDim.x) s[n] = score[b * NBOX + n];
    __syncthreads();

    float mx = -3.0e38f;
    for (int n = tid; n < NBOX; n += blockDim.x) mx = fmaxf(mx, s[n]);
    for (int o = 32; o > 0; o >>= 1) mx = fmaxf(mx, __shfl_down(mx, o));
    if ((tid & 63) == 0) red[tid >> 6] = mx;
    __syncthreads();
    mx = fmaxf(fmaxf(red[0], red[1]), fmaxf(red[2], red[3]));
    __syncthreads();

    float se = 0.f;
    for (int n = tid; n < NBOX; n += blockDim.x) se += expf(s[n] - mx);
    for (int o = 32; o > 0; o >>= 1) se += __shfl_down(se, o);
    if ((tid & 63) == 0) red[tid >> 6] = se;
    __syncthreads();
    se = red[0] + red[1] + red[2] + red[3];

    for (int n = tid; n < NBOX; n += blockDim.x) {
        float v = s[n];
        int rank = 0;
        for (int m = 0; m < NBOX; ++m) {
            float u = s[m];
            rank += (u < v) || (u == v && m < n);
        }
        if (rank >= TOPJ) {
            int k = rank - TOPJ;
            float p = expf(v - mx) / se;
            sel [b * TOPK + k] = n;
            gate[b * TOPK + k] = (1.0f - p) + p;
        }
    }
}

// ================= ROI align 1x1 + gate (e3 NHWC) =================
__global__ void roi_gather(const float* __restrict__ e3, const int* __restrict__ sel,
                           const float* __restrict__ gate, float* __restrict__ out) {
    int bk = blockIdx.x;
    int b = bk / TOPK;
    int n = sel[bk];
    float gt = gate[bk];
    int a   = n / 196;
    int pos = n % 196;
    int i = pos / 14;
    int j = pos % 14;
    int S = a + 1;
    float inv_cnt = 1.0f / (float)(S * S);

    __shared__ int   cidx[9][4];
    __shared__ float cw  [9][4];
    if (threadIdx.x == 0) {
        int t = 0;
        for (int p = 0; p < S; ++p) {
            float yy = (float)j - S * 0.5f + p + 0.5f;   // row coord from j
            float yc = fmaxf(yy, 0.0f);
            int yf = (int)floorf(yc);
            int y_lo, y_hi; float ly;
            if (yf >= 13) { y_lo = 13; y_hi = 13; ly = 0.f; }
            else          { y_lo = yf; y_hi = yf + 1; ly = yc - (float)yf; }
            for (int q = 0; q < S; ++q) {
                float xx = (float)i - S * 0.5f + q + 0.5f;  // col coord from i
                float xc = fmaxf(xx, 0.0f);
                int xf = (int)floorf(xc);
                int x_lo, x_hi; float lx;
                if (xf >= 13) { x_lo = 13; x_hi = 13; lx = 0.f; }
                else          { x_lo = xf; x_hi = xf + 1; lx = xc - (float)xf; }
                cidx[t][0] = y_lo * 14 + x_lo;  cw[t][0] = (1.f - ly) * (1.f - lx);
                cidx[t][1] = y_lo * 14 + x_hi;  cw[t][1] = (1.f - ly) * lx;
                cidx[t][2] = y_hi * 14 + x_lo;  cw[t][2] = ly * (1.f - lx);
                cidx[t][3] = y_hi * 14 + x_hi;  cw[t][3] = ly * lx;
                ++t;
            }
        }
    }
    __syncthreads();
    int NS2 = S * S;
    const float* base = e3 + (long)b * 196 * EMBED;
    for (int c = threadIdx.x; c < EMBED; c += blockDim.x) {
        float acc = 0.f;
        for (int t = 0; t < NS2; ++t) {
            acc += cw[t][0] * base[cidx[t][0] * EMBED + c]
                 + cw[t][1] * base[cidx[t][1] * EMBED + c]
                 + cw[t][2] * base[cidx[t][2] * EMBED + c]
                 + cw[t][3] * base[cidx[t][3] * EMBED + c];
        }
        out[(long)bk * EMBED + c] = acc * inv_cnt * gt;
    }
}

// ================= host launch =================
extern "C" void kernel_launch(void* const* d_in, const int* in_sizes, int n_in,
                              void* d_out, int out_size, void* d_ws, size_t ws_size,
                              hipStream_t stream) {
    const float* x   = (const float*)d_in[0];
    const float* pw1 = (const float*)d_in[1];
    const float* pb1 = (const float*)d_in[2];
    const float* pw2 = (const float*)d_in[3];
    const float* pb2 = (const float*)d_in[4];
    const float* pw3 = (const float*)d_in[5];
    const float* pb3 = (const float*)d_in[6];
    const float* rw1 = (const float*)d_in[7];
    const float* rb1 = (const float*)d_in[8];
    const float* g1  = (const float*)d_in[9];
    const float* b1  = (const float*)d_in[10];
    const float* rw2 = (const float*)d_in[11];
    const float* rb2 = (const float*)d_in[12];
    const float* g2  = (const float*)d_in[13];
    const float* b2  = (const float*)d_in[14];
    const float* rw3 = (const float*)d_in[15];
    const float* rb3 = (const float*)d_in[16];
    const float* g3  = (const float*)d_in[17];
    const float* b3  = (const float*)d_in[18];
    const float* rw4 = (const float*)d_in[19];
    const float* rb4 = (const float*)d_in[20];

    float* ws = (float*)d_ws;
    const long OFF_R1  = 0;
    const long OFF_R1L = 12845056;
    const long OFF_R2  = 19267584;
    const long OFF_S   = 25690112;

    float* r1   = ws + OFF_R1;
    u16*   r1l  = (u16*)(ws + OFF_R1L);
    float* r2   = ws + OFF_R2;
    u16*   r2l  = (u16*)(ws + OFF_R1L);
    float* r3   = ws + OFF_R1;
    float* e1   = ws + OFF_R1 + 3211264;
    float* e2   = ws + OFF_R1 + 6422528;
    float* e3   = ws + OFF_R1 + 8028160;

    float* score = ws + OFF_S;                         // 9408
    float* psum  = score + 9408;                       // up to 128*784 = 100352
    float* psq   = psum + 100352;
    float* coef  = psq + 100352;                       // 512
    float* gate  = coef + 512;                         // 3136
    int*   sel   = (int*)(gate + 3136);                // 3136
    float* partSP= gate + 6272;                        // 9*3136*3 = 84672

    // weight scratch in d_out (fully overwritten by roi_gather at the end)
    float* dout = (float*)d_out;
    float* t_rw1 = dout;                        // 1728 f32
    float* t_rw4 = dout + 1728;                 // 6912 f32
    float* q_pw1 = dout + 8640;                 // 3072 f32 -> end 11712
    u16* w2h = (u16*)(dout + 11712);            // 73728 u16 each
    u16* w2m = (u16*)(dout + 48576);
    u16* w2l = (u16*)(dout + 85440);
    u16* w3h = (u16*)(dout + 122304);           // 294912 u16 each
    u16* w3m = (u16*)(dout + 269760);
    u16* w3l = (u16*)(dout + 417216);
    u16* p2h = (u16*)(dout + 564672);           // 32768 u16 each
    u16* p2l = (u16*)(dout + 581056);
    u16* p3h = (u16*)(dout + 597440);           // 393216 u16 each
    u16* p3l = (u16*)(dout + 794048);           // end 990656 < 2408448

    const int T = 256;
    w_split_all<<<3150, T, 0, stream>>>(rw1, rw2, rw3, rw4, pw1, pw2, pw3,
                                        t_rw1, t_rw4, q_pw1,
                                        w2h, w2m, w2l, w3h, w3m, w3l,
                                        p2h, p2l, p3h, p3l);

    // ---- region-proposal path (3-limb split) ----
    // rp1: x NCHW -> r1 NHWC (16,112,112,64); OCT=32, stats fused (psum[c][784])
    conv_direct_nhwc<3,3,2,1,32,true><<<dim3(784, 2), T, 0, stream>>>(
        x, t_rw1, rb1, r1, psum, psq, 784, 3, 224, 224, 64, 112, 112);
    bn_coef_par<<<64, T, 0, stream>>>(psum, psq, g1, b1, coef, 64, 1.0f / 200704.f, 784);
    split3_bn<<<12544, T, 0, stream>>>(r1, r1l, coef, 63, 3211264);

    // rp2: (16,56,56,128); M=50176, K=576; 1568 blocks (MT=784, NT=2), stats fused
    mfma_conv7<3,3,2,1,6,3,true><<<1568, T, 0, stream>>>(
        (const u32*)r1, r1l, w2h, w2m, w2l, rb2, r2, psum, psq, 2,
        112, 112, 128, 56, 56);
    bn_coef_par<<<128, T, 0, stream>>>(psum, psq, g2, b2, coef, 128, 1.0f / 50176.f, 784);
    split3_bn<<<6272, T, 0, stream>>>(r2, r2l, coef, 127, 1605632);

    // rp3: (16,28,28,256); M=12544, K=1152; 784 blocks (MT=196, NT=4), stats fused
    mfma_conv7<3,3,2,1,7,3,true><<<784, T, 0, stream>>>(
        (const u32*)r2, r2l, w3h, w3m, w3l, rb3, r3, psum, psq, 4,
        56, 56, 256, 28, 28);
    bn_coef_par<<<256, T, 0, stream>>>(psum, psq, g3, b3, coef, 256, 1.0f / 12544.f, 196);

    // rp4 (score): bn3+relu fused, tap-parallel partials
    score_partial<<<(9 * 3136 + T - 1) / T, T, 0, stream>>>(r3, t_rw4, coef, partSP);
    score_reduce<<<(9408 + T - 1) / T, T, 0, stream>>>(partSP, rb4, score);

    // top-K + gate
    topk_kernel<<<16, T, 0, stream>>>(score, sel, gate);

    // ---- patch-embed path (2-limb split) ----
    // patch1: x NCHW -> e1 NHWC (16,56,56,64); OCT=32, no stats
    conv_direct_nhwc<4,4,4,0,32,false><<<dim3(196, 2), T, 0, stream>>>(
        x, q_pw1, pb1, e1, nullptr, nullptr, 0, 3, 224, 224, 64, 56, 56);
    split2_plain<<<3136, T, 0, stream>>>(e1, 802816);
    // patch2: -> e2 (16,28,28,128); 392 blocks (MT=196, NT=2)
    mfma_conv7<2,2,2,0,6,2,false><<<392, T, 0, stream>>>(
        (const u32*)e1, nullptr, p2h, p2l, nullptr, pb2, e2, nullptr, nullptr, 2,
        56, 56, 128, 28, 28);
    split2_plain<<<1568, T, 0, stream>>>(e2, 401408);
    // patch3: -> e3 (16,196,768); 588 blocks (MT=49, NT=12)
    mfma_conv7<2,2,2,0,7,2,false><<<588, T, 0, stream>>>(
        (const u32*)e2, nullptr, p3h, p3l, nullptr, pb3, e3, nullptr, nullptr, 12,
        28, 28, 768, 14, 14);

    // ---- ROI align + gate -> d_out (16,196,768) ----
    roi_gather<<<16 * TOPK, T, 0, stream>>>(e3, sel, gate, (float*)d_out);
}

// Round 17
// 336.039 us; speedup vs baseline: 1.0198x; 1.0198x over previous
//
#include <hip/hip_runtime.h>
#include <math.h>

// ---------------- problem constants ----------------
#define BB 16
#define NBOX 588          // A * 14 * 14
#define TOPJ 392          // J
#define TOPK 196          // K
#define EMBED 768

typedef unsigned short u16;
typedef unsigned int   u32;
using short8 = __attribute__((ext_vector_type(8))) short;
using f32x4  = __attribute__((ext_vector_type(4))) float;

// ---------------- bf16 split helpers ----------------
__device__ inline u16 rnebf(float x) {
    u32 u = __builtin_bit_cast(u32, x);
    u32 r = u + 0x7fff + ((u >> 16) & 1);
    return (u16)(r >> 16);
}
__device__ inline float bfval(u16 h) {
    u32 u = ((u32)h) << 16;
    return __builtin_bit_cast(float, u);
}
// packed-limb unpack: word = (limb0 << 16) | limb1
__device__ inline u32 hi2(u32 w0, u32 w1) { return (w0 >> 16) | (w1 & 0xffff0000u); }
__device__ inline u32 lo2(u32 w0, u32 w1) { return (w0 & 0xffffu) | (w1 << 16); }
__device__ inline u32 pack2(float y) {
    u16 h = rnebf(y);
    u16 l = rnebf(y - bfval(h));
    return ((u32)h << 16) | (u32)l;
}

// ================= fused weight transform + split (1 launch) =================
__global__ void w_split_all(
    const float* __restrict__ rw1, const float* __restrict__ rw2,
    const float* __restrict__ rw3, const float* __restrict__ rw4,
    const float* __restrict__ pw1, const float* __restrict__ pw2,
    const float* __restrict__ pw3,
    float* t1, float* t4, float* q1,
    u16* w2h, u16* w2m, u16* w2l,
    u16* w3h, u16* w3m, u16* w3l,
    u16* p2h, u16* p2l, u16* p3h, u16* p3l)
{
    int i = blockIdx.x * 256 + threadIdx.x;
    if (i < 1728) {        // rw1: Cout=64, Cin=3, KK=9 (conv-order fp32)
        int oc = i % 64; int k = i / 64; int tap = k % 9; int ic = k / 9;
        t1[i] = rw1[(oc * 3 + ic) * 9 + tap];
        return;
    }
    i -= 1728;
    if (i < 73728) {       // rw2: 128 x (9*64), split3
        int oc = i / 576; int rem = i - oc * 576; int tap = rem >> 6; int ic = rem & 63;
        float v = rw2[(oc * 64 + ic) * 9 + tap];
        u16 h = rnebf(v); float r = v - bfval(h);
        u16 m = rnebf(r); float r2 = r - bfval(m);
        w2h[i] = h; w2m[i] = m; w2l[i] = rnebf(r2);
        return;
    }
    i -= 73728;
    if (i < 294912) {      // rw3: 256 x (9*128), split3
        int oc = i / 1152; int rem = i - oc * 1152; int tap = rem >> 7; int ic = rem & 127;
        float v = rw3[(oc * 128 + ic) * 9 + tap];
        u16 h = rnebf(v); float r = v - bfval(h);
        u16 m = rnebf(r); float r2 = r - bfval(m);
        w3h[i] = h; w3m[i] = m; w3l[i] = rnebf(r2);
        return;
    }
    i -= 294912;
    if (i < 6912) {        // rw4: [oc*9+tap][256] fp32
        int ic = i % 256; int t = i / 256; int tap = t % 9; int oc = t / 9;
        t4[i] = rw4[(oc * 256 + ic) * 9 + tap];
        return;
    }
    i -= 6912;
    if (i < 3072) {        // pw1: Cout=64, Cin=3, KK=16 (conv-order fp32)
        int oc = i % 64; int k = i / 64; int tap = k % 16; int ic = k / 16;
        q1[i] = pw1[(oc * 3 + ic) * 16 + tap];
        return;
    }
    i -= 3072;
    if (i < 32768) {       // pw2: 128 x (4*64), split2
        int oc = i >> 8; int rem = i & 255; int tap = rem >> 6; int ic = rem & 63;
        float v = pw2[(oc * 64 + ic) * 4 + tap];
        u16 h = rnebf(v);
        p2h[i] = h; p2l[i] = rnebf(v - bfval(h));
        return;
    }
    i -= 32768;
    if (i < 393216) {      // pw3: 768 x (4*128), split2
        int oc = i >> 9; int rem = i & 511; int tap = rem >> 7; int ic = rem & 127;
        float v = pw3[(oc * 128 + ic) * 4 + tap];
        u16 h = rnebf(v);
        p3h[i] = h; p3l[i] = rnebf(v - bfval(h));
        return;
    }
}

// ================= activation splitter (rp path only; BN dependency) =========
__global__ void split3_bn(float* __restrict__ x, u16* __restrict__ lp,
                          const float* __restrict__ coef, int Cmask, long n4) {
    long i = (long)blockIdx.x * 256 + threadIdx.x;
    if (i >= n4) return;
    float4 v = *reinterpret_cast<const float4*>(x + i * 4);
    int c0 = (int)((i * 4) & Cmask);
    float4 sc = *reinterpret_cast<const float4*>(coef + c0);
    float4 sh = *reinterpret_cast<const float4*>(coef + (Cmask + 1) + c0);
    float y[4] = {fmaxf(fmaf(v.x, sc.x, sh.x), 0.f), fmaxf(fmaf(v.y, sc.y, sh.y), 0.f),
                  fmaxf(fmaf(v.z, sc.z, sh.z), 0.f), fmaxf(fmaf(v.w, sc.w, sh.w), 0.f)};
    u32 w[4]; u16 l[4];
#pragma unroll
    for (int j = 0; j < 4; ++j) {
        u16 h = rnebf(y[j]); float r = y[j] - bfval(h);
        u16 m = rnebf(r);    float r2 = r - bfval(m);
        l[j] = rnebf(r2);
        w[j] = ((u32)h << 16) | (u32)m;
    }
    uint4 wv; wv.x = w[0]; wv.y = w[1]; wv.z = w[2]; wv.w = w[3];
    *reinterpret_cast<uint4*>(x + i * 4) = wv;
    uint2 lv; lv.x = (u32)l[0] | ((u32)l[1] << 16); lv.y = (u32)l[2] | ((u32)l[3] << 16);
    *reinterpret_cast<uint2*>(lp + i * 4) = lv;
}

// ================= direct conv, NCHW in (3ch), NHWC out =================
// STATS: per-block per-channel sum/sumsq -> psum[c][blockIdx.x].
// PACK2: store (h<<16)|l u32 instead of fp32 (patch path; no BN dependency).
template<int KH, int KW, int S, int P, int OCT, bool STATS, bool PACK2>
__global__ __launch_bounds__(256) void conv_direct_nhwc(
    const float* __restrict__ in, const float* __restrict__ wT,
    const float* __restrict__ bias, float* __restrict__ out,
    float* __restrict__ psum, float* __restrict__ psq, int NPART,
    int Cin, int Hin, int Win, int Cout, int Hout, int Wout)
{
    const int hw = Hout * Wout;
    const long total = (long)BB * hw;
    long sp = (long)blockIdx.x * 256 + threadIdx.x;
    if (sp >= total) return;
    int b  = (int)(sp / hw);
    int r  = (int)(sp - (long)b * hw);
    int oy = r / Wout;
    int ox = r - oy * Wout;
    int oc0 = blockIdx.y * OCT;

    float acc[OCT];
#pragma unroll
    for (int i = 0; i < OCT; ++i) acc[i] = bias[oc0 + i];

    int  ixc[KW]; long yoff[KH]; float xm[KW], ym[KH];
#pragma unroll
    for (int kx = 0; kx < KW; ++kx) {
        int ix = ox * S - P + kx;
        xm[kx] = (ix >= 0 && ix < Win) ? 1.f : 0.f;
        ixc[kx] = min(max(ix, 0), Win - 1);
    }
#pragma unroll
    for (int ky = 0; ky < KH; ++ky) {
        int iy = oy * S - P + ky;
        ym[ky] = (iy >= 0 && iy < Hin) ? 1.f : 0.f;
        yoff[ky] = (long)min(max(iy, 0), Hin - 1) * Win;
    }

    const float* ib = in + (long)b * Cin * Hin * Win;
    for (int ic = 0; ic < Cin; ++ic) {
        const float* ip = ib + (long)ic * Hin * Win;
#pragma unroll
        for (int ky = 0; ky < KH; ++ky) {
            const float* row = ip + yoff[ky];
#pragma unroll
            for (int kx = 0; kx < KW; ++kx) {
                float v = row[ixc[kx]];
                if (P > 0) v *= ym[ky] * xm[kx];
                const float* wr = wT + ((long)((ic * KH + ky) * KW + kx)) * Cout + oc0;
#pragma unroll
                for (int i = 0; i < OCT; ++i) acc[i] = fmaf(v, wr[i], acc[i]);
            }
        }
    }
    if (PACK2) {
        u32* op = reinterpret_cast<u32*>(out) + sp * Cout + oc0;
#pragma unroll
        for (int i = 0; i < OCT; i += 4) {
            uint4 v = {pack2(acc[i]), pack2(acc[i+1]), pack2(acc[i+2]), pack2(acc[i+3])};
            *reinterpret_cast<uint4*>(op + i) = v;
        }
    } else {
        float* op = out + sp * Cout + oc0;
#pragma unroll
        for (int i = 0; i < OCT; i += 4) {
            float4 v = {acc[i], acc[i+1], acc[i+2], acc[i+3]};
            *reinterpret_cast<float4*>(op + i) = v;
        }
    }

    if (STATS) {
        __shared__ float sred[4][OCT], qred[4][OCT];
        const int tid = threadIdx.x;
        const int wv = tid >> 6;
        const int ln = tid & 63;
#pragma unroll
        for (int i = 0; i < OCT; ++i) {
            float s = acc[i];
            float q = acc[i] * acc[i];
            for (int o = 32; o > 0; o >>= 1) {
                s += __shfl_down(s, o);
                q += __shfl_down(q, o);
            }
            if (ln == 0) { sred[wv][i] = s; qred[wv][i] = q; }
        }
        __syncthreads();
        if (tid < OCT) {
            float s = sred[0][tid] + sred[1][tid] + sred[2][tid] + sred[3][tid];
            float q = qred[0][tid] + qred[1][tid] + qred[2][tid] + qred[3][tid];
            int c = oc0 + tid;
            psum[(long)c * NPART + blockIdx.x] = s;
            psq [(long)c * NPART + blockIdx.x] = q;
        }
    }
}

// ================= split-bf16 MFMA implicit-GEMM conv (pre-split A) =================
// BM=64 x BN=64 (24KB LDS -> 6 blocks/CU). Bijective XCD-chunk swizzle + n-inner.
// 4 waves 2x2, wave tile 32x32. STATS: psum[c][mt]. PACK2: packed (h<<16)|l out.
#define MBM 64
#define MBN 64
template<int KH, int KW, int S, int P, int CLOG, int NS, bool STATS, bool PACK2>
__global__ __launch_bounds__(256, 6) void mfma_conv7(
    const u32* __restrict__ hm, const u16* __restrict__ lp,
    const u16* __restrict__ w0, const u16* __restrict__ w1, const u16* __restrict__ w2,
    const float* __restrict__ bias, float* __restrict__ out,
    float* __restrict__ psum, float* __restrict__ psq, int NT,
    int Hin, int Win, int Cout, int Hout, int Wout)
{
    const int Cin = 1 << CLOG;
    const int KK = KH * KW;
    const int Ktot = Cin * KK;
    const int hw = Hout * Wout;
    const long Mtot = (long)BB * hw;

    // ---- bijective XCD-chunk swizzle + n-inner decode ----
    const int nwg = gridDim.x;
    const int orig = blockIdx.x;
    const int xcd = orig & 7, pos = orig >> 3;
    const int qc = nwg >> 3, rc = nwg & 7;
    const int logical = (xcd < rc ? xcd * (qc + 1) : rc * (qc + 1) + (xcd - rc) * qc) + pos;
    const int MT = nwg / NT;
    const int mt = logical / NT;
    const int nt = logical - mt * NT;
    const int n0 = nt * MBN;
    const long m0 = (long)mt * MBM;

    __shared__ u16 Asm[NS][MBM * 32];
    __shared__ u16 Bsm[NS][MBN * 32];

    const int tid = threadIdx.x;

    // ---- staging ids: row = tid>>2 (0..63), slot = tid&3 (8 k-elems = 16B) ----
    const int srow = tid >> 2;
    const int slot = tid & 3;
    long sp_g = m0 + srow; if (sp_g >= Mtot) sp_g = Mtot - 1;
    const int gb  = (int)(sp_g / hw);
    const int gr  = (int)(sp_g - (long)gb * hw);
    const int goy = gr / Wout;
    const int gox = gr - goy * Wout;
    const long ibase_e = (long)gb * Hin * Win * Cin;

    uint4 ga0, ga1, gal, b0r, b1r, b2r;

    auto gatherA = [&](int k0) {
        int tap = k0 >> CLOG;
        int ky = tap / KW, kx = tap - ky * KW;
        int icb = (k0 & (Cin - 1)) + slot * 8;
        int iy = goy * S - P + ky;
        int ix = gox * S - P + kx;
        bool ok = true;
        if (P > 0) {
            ok = (iy >= 0 && iy < Hin && ix >= 0 && ix < Win);
            iy = min(max(iy, 0), Hin - 1);
            ix = min(max(ix, 0), Win - 1);
        }
        long e = ibase_e + ((long)iy * Win + ix) * Cin + icb;
        const uint4* ph = reinterpret_cast<const uint4*>(hm + e);   // 8 u32 = 32B
        ga0 = ph[0]; ga1 = ph[1];
        if constexpr (NS == 3)
            gal = *reinterpret_cast<const uint4*>(lp + e);          // 8 u16 = 16B
        if (P > 0 && !ok) {
            uint4 z; z.x = z.y = z.z = z.w = 0u;
            ga0 = z; ga1 = z;
            if constexpr (NS == 3) gal = z;
        }
    };
    auto gatherB = [&](int k0) {
        long eb = (long)(n0 + srow) * Ktot + k0 + slot * 8;
        b0r = *reinterpret_cast<const uint4*>(w0 + eb);
        b1r = *reinterpret_cast<const uint4*>(w1 + eb);
        if constexpr (NS == 3) b2r = *reinterpret_cast<const uint4*>(w2 + eb);
    };
    auto stage = [&]() {
        const int sw = (srow >> 1) & 3;
        const int o = srow * 32 + ((slot ^ sw) << 3);
        uint4 H, M;
        H.x = hi2(ga0.x, ga0.y); H.y = hi2(ga0.z, ga0.w);
        H.z = hi2(ga1.x, ga1.y); H.w = hi2(ga1.z, ga1.w);
        M.x = lo2(ga0.x, ga0.y); M.y = lo2(ga0.z, ga0.w);
        M.z = lo2(ga1.x, ga1.y); M.w = lo2(ga1.z, ga1.w);
        *reinterpret_cast<uint4*>(&Asm[0][o]) = H;
        *reinterpret_cast<uint4*>(&Asm[1][o]) = M;
        if constexpr (NS == 3) *reinterpret_cast<uint4*>(&Asm[2][o]) = gal;
        *reinterpret_cast<uint4*>(&Bsm[0][o]) = b0r;
        *reinterpret_cast<uint4*>(&Bsm[1][o]) = b1r;
        if constexpr (NS == 3) *reinterpret_cast<uint4*>(&Bsm[2][o]) = b2r;
    };

    // ---- compute ids: 4 waves 2x2, wave tile 32x32 ----
    const int w    = tid >> 6;
    const int lane = tid & 63;
    const int wr = w >> 1, wc = w & 1;
    const int l15 = lane & 15;
    const int sl  = lane >> 4;

    f32x4 acc[2][2];
#pragma unroll
    for (int f = 0; f < 2; ++f)
#pragma unroll
        for (int g = 0; g < 2; ++g) acc[f][g] = (f32x4){0.f, 0.f, 0.f, 0.f};

    auto computeChunk = [&]() {
        short8 bfr[2][NS];
#pragma unroll
        for (int g = 0; g < 2; ++g) {
            int br = wc * 32 + g * 16 + l15;
            int bo = br * 32 + ((sl ^ ((br >> 1) & 3)) << 3);
#pragma unroll
            for (int s = 0; s < NS; ++s)
                bfr[g][s] = __builtin_bit_cast(short8,
                    *reinterpret_cast<const uint4*>(&Bsm[s][bo]));
        }
#pragma unroll
        for (int f = 0; f < 2; ++f) {
            int ar = wr * 32 + f * 16 + l15;
            int ao = ar * 32 + ((sl ^ ((ar >> 1) & 3)) << 3);
            short8 a0 = __builtin_bit_cast(short8,
                *reinterpret_cast<const uint4*>(&Asm[0][ao]));
            short8 a1 = __builtin_bit_cast(short8,
                *reinterpret_cast<const uint4*>(&Asm[1][ao]));
            short8 a2;
            if constexpr (NS == 3)
                a2 = __builtin_bit_cast(short8,
                    *reinterpret_cast<const uint4*>(&Asm[2][ao]));
#pragma unroll
            for (int g = 0; g < 2; ++g) {
                acc[f][g] = __builtin_amdgcn_mfma_f32_16x16x32_bf16(a0, bfr[g][0], acc[f][g], 0, 0, 0);
                acc[f][g] = __builtin_amdgcn_mfma_f32_16x16x32_bf16(a0, bfr[g][1], acc[f][g], 0, 0, 0);
                acc[f][g] = __builtin_amdgcn_mfma_f32_16x16x32_bf16(a1, bfr[g][0], acc[f][g], 0, 0, 0);
                if constexpr (NS == 3) {
                    acc[f][g] = __builtin_amdgcn_mfma_f32_16x16x32_bf16(a1, bfr[g][1], acc[f][g], 0, 0, 0);
                    acc[f][g] = __builtin_amdgcn_mfma_f32_16x16x32_bf16(a0, bfr[g][2], acc[f][g], 0, 0, 0);
                    acc[f][g] = __builtin_amdgcn_mfma_f32_16x16x32_bf16(a2, bfr[g][0], acc[f][g], 0, 0, 0);
                }
            }
        }
    };

    const int nch = Ktot / 32;
    gatherA(0); gatherB(0);
    for (int c = 0; c < nch; ++c) {
        __syncthreads();                    // prev compute done reading LDS
        stage();
        __syncthreads();                    // tile staged
        if (c + 1 < nch) { gatherA((c + 1) * 32); gatherB((c + 1) * 32); }
        computeChunk();
    }

    // ---- epilogue: C frag layout col=lane&15, row=(lane>>4)*4+reg ----
    float bv[2];
#pragma unroll
    for (int g = 0; g < 2; ++g) bv[g] = bias[n0 + wc * 32 + g * 16 + l15];
    float ss[2] = {0.f, 0.f}, qq[2] = {0.f, 0.f};
#pragma unroll
    for (int f = 0; f < 2; ++f) {
        long row0 = m0 + wr * 32 + f * 16 + sl * 4;
#pragma unroll
        for (int g = 0; g < 2; ++g) {
            int col = n0 + wc * 32 + g * 16 + l15;
#pragma unroll
            for (int r = 0; r < 4; ++r) {
                long row = row0 + r;
                float y = acc[f][g][r] + bv[g];
                if (row < Mtot) {
                    if (PACK2)
                        reinterpret_cast<u32*>(out)[row * (long)Cout + col] = pack2(y);
                    else
                        out[row * (long)Cout + col] = y;
                }
                if (STATS) { ss[g] += y; qq[g] += y * y; }
            }
        }
    }
    if (STATS) {
        __syncthreads();                        // Asm free now
        float* st = reinterpret_cast<float*>(&Asm[0][0]);   // [64][8]
        float* sq = st + MBN * 8;
        int slotc = wr * 4 + sl;
#pragma unroll
        for (int g = 0; g < 2; ++g) {
            int cl = wc * 32 + g * 16 + l15;
            st[cl * 8 + slotc] = ss[g];
            sq[cl * 8 + slotc] = qq[g];
        }
        __syncthreads();
        if (tid < MBN) {
            float sAcc = 0.f, qAcc = 0.f;
            for (int j = 0; j < 8; ++j) { sAcc += st[tid * 8 + j]; qAcc += sq[tid * 8 + j]; }
            int c = n0 + tid;
            psum[(long)c * MT + mt] = sAcc;
            psq [(long)c * MT + mt] = qAcc;
        }
    }
}

// parallel bn_coef: one block per channel; strided + tree reduce (fixed order).
__global__ void bn_coef_par(const float* __restrict__ psum, const float* __restrict__ psq,
                            const float* __restrict__ gamma, const float* __restrict__ beta,
                            float* __restrict__ coef, int C, float inv_cnt, int nparts) {
    int c = blockIdx.x;
    int tid = threadIdx.x;
    float s = 0.f, q = 0.f;
    for (int p = tid; p < nparts; p += 256) {
        s += psum[(long)c * nparts + p];
        q += psq [(long)c * nparts + p];
    }
    __shared__ float sd[256], qd[256];
    sd[tid] = s; qd[tid] = q;
    __syncthreads();
    for (int o = 128; o > 0; o >>= 1) {
        if (tid < o) { sd[tid] += sd[tid + o]; qd[tid] += qd[tid + o]; }
        __syncthreads();
    }
    if (tid == 0) {
        float mean = sd[0] * inv_cnt;
        float var  = qd[0] * inv_cnt - mean * mean;
        float sc = gamma[c] * rsqrtf(var + 1e-5f);
        coef[c] = sc;
        coef[C + c] = beta[c] - mean * sc;
    }
}

// ================= score conv (rp4): tap-parallel partials + reduce =================
__global__ void score_partial(const float* __restrict__ r3, const float* __restrict__ wT4,
                              const float* __restrict__ coef, float* __restrict__ part) {
    int idx = blockIdx.x * 256 + threadIdx.x;
    if (idx >= 9 * 3136) return;
    int tap = idx / 3136;
    int sp  = idx - tap * 3136;
    int b = sp / 196; int pos = sp - b * 196;
    int oy = pos / 14, ox = pos - oy * 14;
    int ky = tap / 3, kx = tap - ky * 3;
    int iy = oy * 2 - 1 + ky, ix = ox * 2 - 1 + kx;
    float mval = (iy >= 0 && iy < 28 && ix >= 0 && ix < 28) ? 1.f : 0.f;
    iy = min(max(iy, 0), 27); ix = min(max(ix, 0), 27);
    const float* p = r3 + ((long)(b * 28 + iy) * 28 + ix) * 256;
    float a0 = 0.f, a1 = 0.f, a2 = 0.f;
    for (int icv = 0; icv < 64; ++icv) {
        float4 v  = *reinterpret_cast<const float4*>(p + icv * 4);
        float4 sc = *reinterpret_cast<const float4*>(coef + icv * 4);
        float4 sh = *reinterpret_cast<const float4*>(coef + 256 + icv * 4);
        float u[4];
        u[0] = fmaxf(fmaf(v.x, sc.x, sh.x), 0.f);
        u[1] = fmaxf(fmaf(v.y, sc.y, sh.y), 0.f);
        u[2] = fmaxf(fmaf(v.z, sc.z, sh.z), 0.f);
        u[3] = fmaxf(fmaf(v.w, sc.w, sh.w), 0.f);
        float4 w0 = *reinterpret_cast<const float4*>(wT4 + ((0 * 9 + tap) * 256 + icv * 4));
        float4 w1 = *reinterpret_cast<const float4*>(wT4 + ((1 * 9 + tap) * 256 + icv * 4));
        float4 w2 = *reinterpret_cast<const float4*>(wT4 + ((2 * 9 + tap) * 256 + icv * 4));
        a0 += u[0]*w0.x + u[1]*w0.y + u[2]*w0.z + u[3]*w0.w;
        a1 += u[0]*w1.x + u[1]*w1.y + u[2]*w1.z + u[3]*w1.w;
        a2 += u[0]*w2.x + u[1]*w2.y + u[2]*w2.z + u[3]*w2.w;
    }
    part[idx * 3 + 0] = a0 * mval;
    part[idx * 3 + 1] = a1 * mval;
    part[idx * 3 + 2] = a2 * mval;
}

__global__ void score_reduce(const float* __restrict__ part, const float* __restrict__ rb4,
                             float* __restrict__ score) {
    int idx = blockIdx.x * 256 + threadIdx.x;   // 3136*3
    if (idx >= 9408) return;
    int sp = idx / 3; int oc = idx - sp * 3;
    float s = rb4[oc];
    for (int t = 0; t < 9; ++t) s += part[((long)t * 3136 + sp) * 3 + oc];
    int b = sp / 196, pos = sp - b * 196;
    score[b * NBOX + oc * 196 + pos] = s;
}

// ================= top-K (stable ascending rank) + gate =================
__global__ void topk_kernel(const float* __restrict__ score, int* __restrict__ sel,
                            float* __restrict__ gate) {
    int b = blockIdx.x;
    int tid = threadIdx.x;
    __shared__ float s[NBOX];
    __shared__ float red[4];
    for (int n = tid; n < NBOX; n += blockDim.x) s[n] = score[b * NBOX + n];
    __syncthreads();

    float mx = -3.0e38f;
    for (int n = tid; n < NBOX; n += blockDim.x) mx = fmaxf(mx, s[n]);
    for (int o = 32; o > 0; o >>= 1) mx = fmaxf(mx, __shfl_down(mx, o));
    if ((tid & 63) == 0) red[tid >> 6] = mx;
    __syncthreads();
    mx = fmaxf(fmaxf(red[0], red[1]), fmaxf(red[2], red[3]));
    __syncthreads();

    float se = 0.f;
    for (int n = tid; n < NBOX; n += blockDim.x) se += expf(s[n] - mx);
    for (int o = 32; o > 0; o >>= 1) se += __shfl_down(se, o);
    if ((tid & 63) == 0) red[tid >> 6] = se;
    __syncthreads();
    se = red[0] + red[1] + red[2] + red[3];

    for (int n = tid; n < NBOX; n += blockDim.x) {
        float v = s[n];
        int rank = 0;
        for (int m = 0; m < NBOX; ++m) {
            float u = s[m];
            rank += (u < v) || (u == v && m < n);
        }
        if (rank >= TOPJ) {
            int k = rank - TOPJ;
            float p = expf(v - mx) / se;
            sel [b * TOPK + k] = n;
            gate[b * TOPK + k] = (1.0f - p) + p;
        }
    }
}

// ================= ROI align 1x1 + gate (e3 NHWC) =================
__global__ void roi_gather(const float* __restrict__ e3, const int* __restrict__ sel,
                           const float* __restrict__ gate, float* __restrict__ out) {
    int bk = blockIdx.x;
    int b = bk / TOPK;
    int n = sel[bk];
    float gt = gate[bk];
    int a   = n / 196;
    int pos = n % 196;
    int i = pos / 14;
    int j = pos % 14;
    int S = a + 1;
    float inv_cnt = 1.0f / (float)(S * S);

    __shared__ int   cidx[9][4];
    __shared__ float cw  [9][4];
    if (threadIdx.x == 0) {
        int t = 0;
        for (int p = 0; p < S; ++p) {
            float yy = (float)j - S * 0.5f + p + 0.5f;   // row coord from j
            float yc = fmaxf(yy, 0.0f);
            int yf = (int)floorf(yc);
            int y_lo, y_hi; float ly;
            if (yf >= 13) { y_lo = 13; y_hi = 13; ly = 0.f; }
            else          { y_lo = yf; y_hi = yf + 1; ly = yc - (float)yf; }
            for (int q = 0; q < S; ++q) {
                float xx = (float)i - S * 0.5f + q + 0.5f;  // col coord from i
                float xc = fmaxf(xx, 0.0f);
                int xf = (int)floorf(xc);
                int x_lo, x_hi; float lx;
                if (xf >= 13) { x_lo = 13; x_hi = 13; lx = 0.f; }
                else          { x_lo = xf; x_hi = xf + 1; lx = xc - (float)xf; }
                cidx[t][0] = y_lo * 14 + x_lo;  cw[t][0] = (1.f - ly) * (1.f - lx);
                cidx[t][1] = y_lo * 14 + x_hi;  cw[t][1] = (1.f - ly) * lx;
                cidx[t][2] = y_hi * 14 + x_lo;  cw[t][2] = ly * (1.f - lx);
                cidx[t][3] = y_hi * 14 + x_hi;  cw[t][3] = ly * lx;
                ++t;
            }
        }
    }
    __syncthreads();
    int NS2 = S * S;
    const float* base = e3 + (long)b * 196 * EMBED;
    for (int c = threadIdx.x; c < EMBED; c += blockDim.x) {
        float acc = 0.f;
        for (int t = 0; t < NS2; ++t) {
            acc += cw[t][0] * base[cidx[t][0] * EMBED + c]
                 + cw[t][1] * base[cidx[t][1] * EMBED + c]
                 + cw[t][2] * base[cidx[t][2] * EMBED + c]
                 + cw[t][3] * base[cidx[t][3] * EMBED + c];
        }
        out[(long)bk * EMBED + c] = acc * inv_cnt * gt;
    }
}

// ================= host launch =================
extern "C" void kernel_launch(void* const* d_in, const int* in_sizes, int n_in,
                              void* d_out, int out_size, void* d_ws, size_t ws_size,
                              hipStream_t stream) {
    const float* x   = (const float*)d_in[0];
    const float* pw1 = (const float*)d_in[1];
    const float* pb1 = (const float*)d_in[2];
    const float* pw2 = (const float*)d_in[3];
    const float* pb2 = (const float*)d_in[4];
    const float* pw3 = (const float*)d_in[5];
    const float* pb3 = (const float*)d_in[6];
    const float* rw1 = (const float*)d_in[7];
    const float* rb1 = (const float*)d_in[8];
    const float* g1  = (const float*)d_in[9];
    const float* b1  = (const float*)d_in[10];
    const float* rw2 = (const float*)d_in[11];
    const float* rb2 = (const float*)d_in[12];
    const float* g2  = (const float*)d_in[13];
    const float* b2  = (const float*)d_in[14];
    const float* rw3 = (const float*)d_in[15];
    const float* rb3 = (const float*)d_in[16];
    const float* g3  = (const float*)d_in[17];
    const float* b3  = (const float*)d_in[18];
    const float* rw4 = (const float*)d_in[19];
    const float* rb4 = (const float*)d_in[20];

    float* ws = (float*)d_ws;
    const long OFF_R1  = 0;
    const long OFF_R1L = 12845056;
    const long OFF_R2  = 19267584;
    const long OFF_S   = 25690112;

    float* r1   = ws + OFF_R1;
    u16*   r1l  = (u16*)(ws + OFF_R1L);
    float* r2   = ws + OFF_R2;
    u16*   r2l  = (u16*)(ws + OFF_R1L);
    float* r3   = ws + OFF_R1;
    float* e1   = ws + OFF_R1 + 3211264;
    float* e2   = ws + OFF_R1 + 6422528;
    float* e3   = ws + OFF_R1 + 8028160;

    float* score = ws + OFF_S;                         // 9408
    float* psum  = score + 9408;                       // up to 128*784 = 100352
    float* psq   = psum + 100352;
    float* coef  = psq + 100352;                       // 512
    float* gate  = coef + 512;                         // 3136
    int*   sel   = (int*)(gate + 3136);                // 3136
    float* partSP= gate + 6272;                        // 9*3136*3 = 84672

    // weight scratch in d_out (fully overwritten by roi_gather at the end)
    float* dout = (float*)d_out;
    float* t_rw1 = dout;                        // 1728 f32
    float* t_rw4 = dout + 1728;                 // 6912 f32
    float* q_pw1 = dout + 8640;                 // 3072 f32 -> end 11712
    u16* w2h = (u16*)(dout + 11712);            // 73728 u16 each
    u16* w2m = (u16*)(dout + 48576);
    u16* w2l = (u16*)(dout + 85440);
    u16* w3h = (u16*)(dout + 122304);           // 294912 u16 each
    u16* w3m = (u16*)(dout + 269760);
    u16* w3l = (u16*)(dout + 417216);
    u16* p2h = (u16*)(dout + 564672);           // 32768 u16 each
    u16* p2l = (u16*)(dout + 581056);
    u16* p3h = (u16*)(dout + 597440);           // 393216 u16 each
    u16* p3l = (u16*)(dout + 794048);           // end 990656 < 2408448

    const int T = 256;
    w_split_all<<<3150, T, 0, stream>>>(rw1, rw2, rw3, rw4, pw1, pw2, pw3,
                                        t_rw1, t_rw4, q_pw1,
                                        w2h, w2m, w2l, w3h, w3m, w3l,
                                        p2h, p2l, p3h, p3l);

    // ---- region-proposal path (3-limb split) ----
    // rp1: x NCHW -> r1 NHWC (16,112,112,64); OCT=32, stats fused (psum[c][784])
    conv_direct_nhwc<3,3,2,1,32,true,false><<<dim3(784, 2), T, 0, stream>>>(
        x, t_rw1, rb1, r1, psum, psq, 784, 3, 224, 224, 64, 112, 112);
    bn_coef_par<<<64, T, 0, stream>>>(psum, psq, g1, b1, coef, 64, 1.0f / 200704.f, 784);
    split3_bn<<<12544, T, 0, stream>>>(r1, r1l, coef, 63, 3211264);

    // rp2: (16,56,56,128); M=50176, K=576; 1568 blocks (MT=784, NT=2), stats fused
    mfma_conv7<3,3,2,1,6,3,true,false><<<1568, T, 0, stream>>>(
        (const u32*)r1, r1l, w2h, w2m, w2l, rb2, r2, psum, psq, 2,
        112, 112, 128, 56, 56);
    bn_coef_par<<<128, T, 0, stream>>>(psum, psq, g2, b2, coef, 128, 1.0f / 50176.f, 784);
    split3_bn<<<6272, T, 0, stream>>>(r2, r2l, coef, 127, 1605632);

    // rp3: (16,28,28,256); M=12544, K=1152; 784 blocks (MT=196, NT=4), stats fused
    mfma_conv7<3,3,2,1,7,3,true,false><<<784, T, 0, stream>>>(
        (const u32*)r2, r2l, w3h, w3m, w3l, rb3, r3, psum, psq, 4,
        56, 56, 256, 28, 28);
    bn_coef_par<<<256, T, 0, stream>>>(psum, psq, g3, b3, coef, 256, 1.0f / 12544.f, 196);

    // rp4 (score): bn3+relu fused, tap-parallel partials
    score_partial<<<(9 * 3136 + T - 1) / T, T, 0, stream>>>(r3, t_rw4, coef, partSP);
    score_reduce<<<(9408 + T - 1) / T, T, 0, stream>>>(partSP, rb4, score);

    // top-K + gate
    topk_kernel<<<16, T, 0, stream>>>(score, sel, gate);

    // ---- patch-embed path (2-limb split, PACKED epilogues: no repack passes) ----
    // patch1: x NCHW -> e1 packed (h<<16)|l (16,56,56,64); OCT=32
    conv_direct_nhwc<4,4,4,0,32,false,true><<<dim3(196, 2), T, 0, stream>>>(
        x, q_pw1, pb1, e1, nullptr, nullptr, 0, 3, 224, 224, 64, 56, 56);
    // patch2: -> e2 packed (16,28,28,128); 392 blocks (MT=196, NT=2)
    mfma_conv7<2,2,2,0,6,2,false,true><<<392, T, 0, stream>>>(
        (const u32*)e1, nullptr, p2h, p2l, nullptr, pb2, e2, nullptr, nullptr, 2,
        56, 56, 128, 28, 28);
    // patch3: -> e3 fp32 (16,196,768); 588 blocks (MT=49, NT=12)
    mfma_conv7<2,2,2,0,7,2,false,false><<<588, T, 0, stream>>>(
        (const u32*)e2, nullptr, p3h, p3l, nullptr, pb3, e3, nullptr, nullptr, 12,
        28, 28, 768, 14, 14);

    // ---- ROI align + gate -> d_out (16,196,768) ----
    roi_gather<<<16 * TOPK, T, 0, stream>>>(e3, sel, gate, (float*)d_out);
}